// Round 5
// baseline (30.846 us; speedup 1.0000x reference)
//
#include <hip/hip_runtime.h>
#include <cstdint>

// LDS-only drain: orders intra-wave LDS writes->reads WITHOUT draining vmcnt,
// so in-flight global prefetches survive across it (unlike __syncthreads).
// Single-wave workgroup => lockstep => this is a full sync for LDS state.
#define WAVE_SYNC() asm volatile("s_waitcnt lgkmcnt(0)" ::: "memory")

namespace {

constexpr int N    = 20000;   // nodes
constexpr int D    = 128;     // feature dim
constexpr int DEG  = 32;      // neighbors per node
constexpr int BB   = 1024;    // batch
constexpr int T    = 8;       // walk_times
constexpr int NW   = (N + 31) / 32;  // 625 mask words
constexpr int MAXC = 384;     // list bound (true max 32 + 8*32 = 288)

__device__ __forceinline__ uint32_t rotl32(uint32_t x, int n) {
  return (x << n) | (x >> (32 - n));
}

// Threefry-2x32, 20 rounds (Random123 / JAX threefry2x32_p).
__device__ __forceinline__ void threefry2x32(uint32_t k0, uint32_t k1,
                                             uint32_t x0, uint32_t x1,
                                             uint32_t& o0, uint32_t& o1) {
  const uint32_t ks2 = k0 ^ k1 ^ 0x1BD11BDAu;
  x0 += k0; x1 += k1;
#define TF_ROUND(r) { x0 += x1; x1 = rotl32(x1, (r)); x1 ^= x0; }
  TF_ROUND(13) TF_ROUND(15) TF_ROUND(26) TF_ROUND(6)
  x0 += k1;  x1 += ks2 + 1u;
  TF_ROUND(17) TF_ROUND(29) TF_ROUND(16) TF_ROUND(24)
  x0 += ks2; x1 += k0 + 2u;
  TF_ROUND(13) TF_ROUND(15) TF_ROUND(26) TF_ROUND(6)
  x0 += k0;  x1 += k1 + 3u;
  TF_ROUND(17) TF_ROUND(29) TF_ROUND(16) TF_ROUND(24)
  x0 += k1;  x1 += ks2 + 4u;
  TF_ROUND(13) TF_ROUND(15) TF_ROUND(26) TF_ROUND(6)
  x0 += ks2; x1 += k0 + 5u;
#undef TF_ROUND
  o0 = x0; o1 = x1;
}

// One candidate's 32 random bits for (key, flat index j): o0 ^ o1.
__device__ __forceinline__ uint32_t rbits(uint32_t k0, uint32_t k1, uint32_t j) {
  uint32_t o0, o1;
  threefry2x32(k0, k1, 0u, j, o0, o1);
  return o0 ^ o1;
}

// Exact jax.random.gumbel f32 pipeline (step 0 only): mant = top 23 bits;
// u = mant*2^-23 (or f32 tiny); g = -fl32(log(fl32(-log(u)))).
__device__ __forceinline__ float gumbel_f32(uint32_t bits) {
  const uint32_t mant = bits >> 9;
  const float u = (mant == 0u) ? 1.17549435e-38f
                               : (__uint_as_float(0x3F800000u | mant) - 1.0f);
  const float inner = -(float)log((double)u);
  return -(float)log((double)inner);
}

__global__ __launch_bounds__(64)
void walk_kernel(const float* __restrict__ features,
                 const float* __restrict__ W,
                 const float* __restrict__ bptr,
                 const int*   __restrict__ neighbors,
                 const int*   __restrict__ train_index,
                 int* __restrict__ out)
{
  __shared__ uint32_t candM[NW];    // "ever was a candidate" (never cleared:
                                    //  any unlisted candM node is chosen)
  __shared__ uint32_t chosenM[NW];  // chosen/visited (monotone)
  __shared__ int      lst[2][MAXC];
  __shared__ float    val0[DEG];    // step-0 scores (val==1 for all later steps)
  __shared__ int      cnts[2];
  __shared__ int      pcnt;
  __shared__ int      pendC[16];    // chosen-but-listed candidates (<=9)
  __shared__ float    pendV[16];
  __shared__ uint32_t skey[T][2];

  const int lane = threadIdx.x;
  const int r    = blockIdx.x;
  const int self = train_index[r];
  const uint32_t rN = (uint32_t)(r * N);

  // issue self-neighbor row load ASAP (hides under clears/keygen)
  int nbj = -1;
  if (lane < DEG) nbj = neighbors[(size_t)self * DEG + lane];

  for (int i = lane; i < NW; i += 64) { candM[i] = 0u; chosenM[i] = 0u; }
  if (lane < T) {  // step keys: jax.random.split(key(42), 8), partitionable
    uint32_t o0, o1;
    threefry2x32(0u, 42u, 0u, (uint32_t)lane, o0, o1);
    skey[lane][0] = o0; skey[lane][1] = o1;
  }
  if (lane == 0) { cnts[0] = 0; cnts[1] = 0; pcnt = 0; }

  // ---- step-0 scores (fold order bit-identical to passing versions) ----
  const float bval = bptr[0];
  const float* frow = features + (size_t)self * D;
  float acc = frow[lane] * W[lane] + frow[lane + 64] * W[lane + 64];
  for (int m = 1; m < 64; m <<= 1) acc += __shfl_xor(acc, m);
  const float sx = acc;   // identical across lanes, in-register

  float sval = 0.0f;
  if (lane < DEG) {
    const float* g  = features + (size_t)nbj * D;
    const float* wy = W + D;
    float a = 0.0f;
    for (int d = 0; d < D; d += 4) {
      const float4 f = *reinterpret_cast<const float4*>(g + d);
      const float4 w = *reinterpret_cast<const float4*>(wy + d);
      a += f.x * w.x; a += f.y * w.y; a += f.z * w.z; a += f.w * w.w;
    }
    sval = fmaxf((sx + a) + bval, 0.0f);
  }
  WAVE_SYNC();  // clears/cnts visible
  if (lane < DEG && nbj != self && sval > 0.0f) {  // build step-0 list, dedup
    const uint32_t w = (uint32_t)nbj >> 5, bit = 1u << (nbj & 31);
    const uint32_t old = atomicOr(&candM[w], bit);
    if (!(old & bit)) {
      const int p = atomicAdd(&cnts[0], 1);
      lst[0][p] = nbj; val0[p] = sval;
    }
  }
  WAVE_SYNC();
  if (lane == 0) {
    chosenM[(uint32_t)self >> 5] |= 1u << (self & 31);   // chosen = self_oh
    if (cnts[0] == 0) {  // pre-scan fallback mutates the carry: candi = self_oh
      lst[0][0] = self; val0[0] = 1.0f; cnts[0] = 1;
      candM[(uint32_t)self >> 5] |= 1u << (self & 31);
    }
  }

  int cur = 0;
  for (int k = 0; k < T; ++k) {
    WAVE_SYNC();  // prior step's list/cnt writes visible
    const int cnt = cnts[cur];
    const uint32_t kk0 = skey[k][0], kk1 = skey[k][1];
    int nn;  // new node, computed identically in all lanes (no LDS broadcast)

    if (k == 0) {  // scored step: v = log(s) + gumbel, exact f32 pipeline
      float bv = -__builtin_huge_valf(); int bc = 0x7FFFFFFF;
      for (int i = lane; i < cnt; i += 64) {  // <=32: one iteration
        const int c = lst[cur][i];
        const float v = (float)log((double)val0[i])
                      + gumbel_f32(rbits(kk0, kk1, rN + (uint32_t)c));
        if (v > bv || (v == bv && c < bc)) { bv = v; bc = c; }
      }
      for (int m = 1; m < 64; m <<= 1) {
        const float ov = __shfl_xor(bv, m); const int oc = __shfl_xor(bc, m);
        if (ov > bv || (ov == bv && oc < bc)) { bv = ov; bc = oc; }
      }
      nn = (bc == 0x7FFFFFFF) ? self : bc;
    } else {
      // steps>=1: logp==0 and gumbel strictly monotone in top-23-bit mantissa
      // -> argmax(g) == argmax(mant); ties -> smallest index (first occurrence).
      // Two independent accumulators for threefry ILP; max+total-order-tiebreak
      // is associative/commutative so the merge is exact.
      uint32_t bk0 = 0u, bk1 = 0u; int bc0 = 0x7FFFFFFF, bc1 = 0x7FFFFFFF;
      for (int i = lane; i < cnt; i += 128) {
        const int c = lst[cur][i];
        const uint32_t key = rbits(kk0, kk1, rN + (uint32_t)c) >> 9;
        if (key > bk0 || (key == bk0 && c < bc0)) { bk0 = key; bc0 = c; }
        const int i2 = i + 64;
        if (i2 < cnt) {
          const int c2 = lst[cur][i2];
          const uint32_t key2 = rbits(kk0, kk1, rN + (uint32_t)c2) >> 9;
          if (key2 > bk1 || (key2 == bk1 && c2 < bc1)) { bk1 = key2; bc1 = c2; }
        }
      }
      if (bk1 > bk0 || (bk1 == bk0 && bc1 < bc0)) { bk0 = bk1; bc0 = bc1; }
      for (int m = 1; m < 64; m <<= 1) {
        const uint32_t ok = (uint32_t)__shfl_xor((int)bk0, m);
        const int      oc = __shfl_xor(bc0, m);
        if (ok > bk0 || (ok == bk0 && oc < bc0)) { bk0 = ok; bc0 = oc; }
      }
      nn = (bc0 == 0x7FFFFFFF) ? self : bc0;
    }

    // issue dependent neighbor-row load NOW; no vmcnt drain until first use,
    // so it overlaps the retention scan below (L2-resident: 2.56 MB < 4 MB/XCD)
    int nb = 0;
    if (lane < DEG) nb = neighbors[(size_t)nn * DEG + lane];

    if (lane == 0) {
      out[r * (T + 1) + k + 1] = nn;
      chosenM[(uint32_t)nn >> 5] |= 1u << (nn & 31);  // visible by pending/(b)
      cnts[cur ^ 1] = 0; pcnt = 0;
    }
    WAVE_SYNC();  // cnt/pcnt resets visible before atomics (lgkm only!)

    // retention: !chosen -> keep unconditionally ((v-0)+ad >= v > 0);
    // chosen -> pending (<=9), resolved once nb arrives. The just-chosen nn
    // is tested locally (c != nn) to avoid a same-step LDS RAW on chosenM.
    for (int i = lane; i < cnt; i += 64) {
      const int c = lst[cur][i];
      const uint32_t w = (uint32_t)c >> 5, bit = 1u << (c & 31);
      const bool keep = (c != nn) && !(chosenM[w] & bit);
      const uint64_t act = __ballot(1);
      const uint64_t mk  = __ballot(keep);
      const int ldr = (int)(__ffsll((unsigned long long)act) - 1);
      int base = 0;
      if (lane == ldr) base = atomicAdd(&cnts[cur ^ 1], (int)__popcll(mk));
      base = __shfl(base, ldr);
      if (keep) {
        lst[cur ^ 1][base + (int)__popcll(mk & ((1ULL << lane) - 1ULL))] = c;
      } else {
        const int q = atomicAdd(&pcnt, 1);
        pendC[q] = c; pendV[q] = (k == 0) ? val0[i] : 1.0f;
      }
    }
    WAVE_SYNC();  // lst/pend writes visible (vm prefetch still in flight)

    if (lane < DEG) {  // first use of nb => compiler-inserted vmcnt wait here
      // resolve pending: exact reference f32 semantics (v - 1) + ad > 0
      const int pn = pcnt;
      for (int q = 0; q < pn; ++q) {
        const int p = pendC[q];
        const bool isadj = __any(nb == p);
        if (lane == 0) {
          if ((pendV[q] - 1.0f) + (isadj ? 1.0f : 0.0f) > 0.0f) {
            const int pp = atomicAdd(&cnts[cur ^ 1], 1);
            lst[cur ^ 1][pp] = p;
          }
        }
      }
      // (b) fresh adj members: add iff not chosen and never-listed (dedup candM).
      // candM-without-clear is sound: unlisted candM nodes are necessarily chosen.
      const uint32_t w = (uint32_t)nb >> 5, bit = 1u << (nb & 31);
      if (!(chosenM[w] & bit) && !(candM[w] & bit)) {
        const uint32_t old = atomicOr(&candM[w], bit);
        if (!(old & bit)) {
          const int pp = atomicAdd(&cnts[cur ^ 1], 1);
          lst[cur ^ 1][pp] = nb;
        }
      }
    }
    cur ^= 1;
  }
  if (lane == 0) out[r * (T + 1)] = self;
}

}  // namespace

extern "C" void kernel_launch(void* const* d_in, const int* in_sizes, int n_in,
                              void* d_out, int out_size, void* d_ws, size_t ws_size,
                              hipStream_t stream) {
  const float* features  = (const float*)d_in[0];
  const float* W         = (const float*)d_in[1];
  const float* b         = (const float*)d_in[2];
  const int*   neighbors = (const int*)d_in[3];
  const int*   tindex    = (const int*)d_in[4];
  int* out = (int*)d_out;

  hipLaunchKernelGGL(walk_kernel, dim3(BB), dim3(64), 0, stream,
                     features, W, b, neighbors, tindex, out);
}

// Round 6
// 25.555 us; speedup vs baseline: 1.2071x; 1.2071x over previous
//
#include <hip/hip_runtime.h>
#include <cstdint>

namespace {

constexpr int N    = 20000;   // nodes
constexpr int D    = 128;     // feature dim
constexpr int DEG  = 32;      // neighbors per node
constexpr int BB   = 1024;    // batch
constexpr int T    = 8;       // walk_times
constexpr int NW   = (N + 31) / 32;  // 625 mask words
constexpr int MAXC = 384;     // list bound (true max 32 + 8*32 = 288)

__device__ __forceinline__ uint32_t rotl32(uint32_t x, int n) {
  return (x << n) | (x >> (32 - n));
}

// Threefry-2x32, 20 rounds (Random123 / JAX threefry2x32_p).
__device__ __forceinline__ void threefry2x32(uint32_t k0, uint32_t k1,
                                             uint32_t x0, uint32_t x1,
                                             uint32_t& o0, uint32_t& o1) {
  const uint32_t ks2 = k0 ^ k1 ^ 0x1BD11BDAu;
  x0 += k0; x1 += k1;
#define TF_ROUND(r) { x0 += x1; x1 = rotl32(x1, (r)); x1 ^= x0; }
  TF_ROUND(13) TF_ROUND(15) TF_ROUND(26) TF_ROUND(6)
  x0 += k1;  x1 += ks2 + 1u;
  TF_ROUND(17) TF_ROUND(29) TF_ROUND(16) TF_ROUND(24)
  x0 += ks2; x1 += k0 + 2u;
  TF_ROUND(13) TF_ROUND(15) TF_ROUND(26) TF_ROUND(6)
  x0 += k0;  x1 += k1 + 3u;
  TF_ROUND(17) TF_ROUND(29) TF_ROUND(16) TF_ROUND(24)
  x0 += k1;  x1 += ks2 + 4u;
  TF_ROUND(13) TF_ROUND(15) TF_ROUND(26) TF_ROUND(6)
  x0 += ks2; x1 += k0 + 5u;
#undef TF_ROUND
  o0 = x0; o1 = x1;
}

// One candidate's 32 random bits for (key, flat index j): o0 ^ o1.
__device__ __forceinline__ uint32_t rbits(uint32_t k0, uint32_t k1, uint32_t j) {
  uint32_t o0, o1;
  threefry2x32(k0, k1, 0u, j, o0, o1);
  return o0 ^ o1;
}

// Exact jax.random.gumbel f32 pipeline (step 0 only): mant = top 23 bits;
// u = mant*2^-23 (or f32 tiny); g = -fl32(log(fl32(-log(u)))).
__device__ __forceinline__ float gumbel_f32(uint32_t bits) {
  const uint32_t mant = bits >> 9;
  const float u = (mant == 0u) ? 1.17549435e-38f
                               : (__uint_as_float(0x3F800000u | mant) - 1.0f);
  const float inner = -(float)log((double)u);
  return -(float)log((double)inner);
}

// Monotone (order-preserving) f32 -> u32 map for finite floats.
__device__ __forceinline__ uint32_t f2ord(float f) {
  const uint32_t b = __float_as_uint(f);
  return (b & 0x80000000u) ? ~b : (b | 0x80000000u);
}

template <int CTRL>
__device__ __forceinline__ uint32_t dppmov(uint32_t v) {
  // old = v: lanes with no valid source keep their own value (identity for max)
  return (uint32_t)__builtin_amdgcn_update_dpp((int)v, (int)v, CTRL, 0xF, 0xF, false);
}

// Exact wave64 max of packed (hi:lo) u64; result broadcast to all lanes.
// row_shr:1/2/4/8 -> lanes 15/31/47/63 hold row maxima; bcast15 merges row
// pairs at lanes 31/63; bcast31 merges all at lane 63. VALU-speed (no DS ops).
__device__ __forceinline__ void wave_max64(uint32_t& hi, uint32_t& lo) {
#define RL(CTRL) { const uint32_t oh = dppmov<CTRL>(hi), ol = dppmov<CTRL>(lo); \
    if (oh > hi || (oh == hi && ol > lo)) { hi = oh; lo = ol; } }
  RL(0x111) RL(0x112) RL(0x114) RL(0x118) RL(0x142) RL(0x143)
#undef RL
  hi = (uint32_t)__builtin_amdgcn_readlane((int)hi, 63);
  lo = (uint32_t)__builtin_amdgcn_readlane((int)lo, 63);
}

__global__ __launch_bounds__(64)
void walk_kernel(const float* __restrict__ features,
                 const float* __restrict__ W,
                 const float* __restrict__ bptr,
                 const int*   __restrict__ neighbors,
                 const int*   __restrict__ train_index,
                 int* __restrict__ out)
{
  __shared__ uint32_t candM[NW];    // "ever was a candidate" (never cleared:
                                    //  any unlisted candM node is chosen)
  __shared__ uint32_t chosenM[NW];  // chosen/visited (monotone)
  __shared__ int      lst[2][MAXC];
  __shared__ float    val0[DEG];    // step-0 scores (val==1 for later steps)
  __shared__ int      pendC[16];    // chosen-but-listed candidates (<=9)
  __shared__ float    pendV[16];

  const int lane = threadIdx.x;
  const int r    = blockIdx.x;
  const int self = train_index[r];
  const uint32_t rN = (uint32_t)(r * N);
  const uint64_t lower = (1ULL << lane) - 1ULL;

  // issue self-neighbor row load ASAP
  int nbj = -1;
  if (lane < DEG) nbj = neighbors[(size_t)self * DEG + lane];

  for (int i = lane; i < NW; i += 64) { candM[i] = 0u; chosenM[i] = 0u; }

  // step keys: jax.random.split(key(42), 8) partitionable; lane k holds key k.
  uint32_t sk0, sk1;
  threefry2x32(0u, 42u, 0u, (uint32_t)lane, sk0, sk1);

  // ---- step-0 scores (fold order bit-identical to passing versions) ----
  const float bval = bptr[0];
  const float* frow = features + (size_t)self * D;
  float acc = frow[lane] * W[lane] + frow[lane + 64] * W[lane + 64];
  for (int m = 1; m < 64; m <<= 1) acc += __shfl_xor(acc, m);
  const float sx = acc;

  float sval = 0.0f;
  if (lane < DEG) {
    const float* g  = features + (size_t)nbj * D;
    const float* wy = W + D;
    float a = 0.0f;
    for (int d = 0; d < D; d += 4) {
      const float4 f = *reinterpret_cast<const float4*>(g + d);
      const float4 w = *reinterpret_cast<const float4*>(wy + d);
      a += f.x * w.x; a += f.y * w.y; a += f.z * w.z; a += f.w * w.w;
    }
    sval = fmaxf((sx + a) + bval, 0.0f);
  }

  // build step-0 list {c != self : s_c > 0}; dedup via candM atomicOr;
  // slots via ballot prefix (list order is semantically irrelevant).
  bool add0 = false;
  if (lane < DEG && nbj != self && sval > 0.0f) {
    const uint32_t w = (uint32_t)nbj >> 5, bit = 1u << (nbj & 31);
    const uint32_t old = atomicOr(&candM[w], bit);
    add0 = !(old & bit);
  }
  const uint64_t m0 = __ballot(add0);
  if (add0) {
    const int p = (int)__popcll(m0 & lower);
    lst[0][p] = nbj; val0[p] = sval;
  }
  int cnt = (int)__popcll(m0);
  if (lane == 0) {
    chosenM[(uint32_t)self >> 5] |= 1u << (self & 31);   // chosen = self_oh
    if (cnt == 0) {  // pre-scan fallback mutates the carry: candi = self_oh
      lst[0][0] = self; val0[0] = 1.0f;
      candM[(uint32_t)self >> 5] |= 1u << (self & 31);
    }
  }
  if (cnt == 0) cnt = 1;

  int cur = 0;
  for (int k = 0; k < T; ++k) {
    const uint32_t kk0 = (uint32_t)__builtin_amdgcn_readlane((int)sk0, k);
    const uint32_t kk1 = (uint32_t)__builtin_amdgcn_readlane((int)sk1, k);

    // ---- argmax via packed u64 max: hi = sort key, lo = 0x7FFFFFFF - c
    // (max hi, then max lo == min c: exactly jnp.argmax's first-occurrence).
    uint32_t hi = 0u, lo = 0u;   // identity: below any real candidate
    if (k == 0) {  // scored: v = log(s) + gumbel, exact f32 pipeline, <=32 cands
      for (int i = lane; i < cnt; i += 64) {
        const int c = lst[cur][i];
        const float v = (float)log((double)val0[i])
                      + gumbel_f32(rbits(kk0, kk1, rN + (uint32_t)c));
        const uint32_t h = f2ord(v), l = 0x7FFFFFFFu - (uint32_t)c;
        if (h > hi || (h == hi && l > lo)) { hi = h; lo = l; }
      }
    } else {
      // steps>=1: logp==0; gumbel strictly monotone in top-23-bit mantissa
      // -> argmax(g) == argmax(mant); ties -> smallest node id. 2-way ILP.
      for (int i = lane; i < cnt; i += 128) {
        const int c = lst[cur][i];
        const uint32_t h = rbits(kk0, kk1, rN + (uint32_t)c) >> 9;
        const uint32_t l = 0x7FFFFFFFu - (uint32_t)c;
        uint32_t h2 = 0u, l2 = 0u;
        const int i2 = i + 64;
        if (i2 < cnt) {
          const int c2 = lst[cur][i2];
          h2 = rbits(kk0, kk1, rN + (uint32_t)c2) >> 9;
          l2 = 0x7FFFFFFFu - (uint32_t)c2;
        }
        if (h  > hi || (h  == hi && l  > lo)) { hi = h;  lo = l;  }
        if (h2 > hi || (h2 == hi && l2 > lo)) { hi = h2; lo = l2; }
      }
    }
    wave_max64(hi, lo);
    const int nn = (lo == 0u) ? self : (int)(0x7FFFFFFFu - lo);  // empty -> self

    // dependent neighbor-row load; overlaps the retention scan below
    int nb = -1;
    if (lane < DEG) nb = neighbors[(size_t)nn * DEG + lane];

    if (lane == 0) {
      out[r * (T + 1) + k + 1] = nn;
      chosenM[(uint32_t)nn >> 5] |= 1u << (nn & 31);  // same-wave DS in-order
    }

    // ---- retention (register bookkeeping, ballot-prefix compaction) ----
    // !chosen -> keep unconditionally ((v-0)+ad >= v > 0);
    // chosen -> pending, resolved after nb arrives (exact (v-1)+ad > 0).
    int nc = 0, pc = 0;
    for (int i0 = 0; i0 < cnt; i0 += 64) {
      const int i = i0 + lane;
      const bool valid = (i < cnt);
      int c = 0;
      if (valid) c = lst[cur][i];
      bool keep = false, pnd = false;
      if (valid) {
        const uint32_t w = (uint32_t)c >> 5, bit = 1u << (c & 31);
        const bool ch = (c == nn) || ((chosenM[w] & bit) != 0u);
        keep = !ch; pnd = ch;
      }
      const uint64_t mk = __ballot(keep);
      const uint64_t mp = __ballot(pnd);
      if (keep) lst[cur ^ 1][nc + (int)__popcll(mk & lower)] = c;
      if (pnd) {
        const int q = pc + (int)__popcll(mp & lower);
        pendC[q] = c; pendV[q] = (k == 0) ? val0[i] : 1.0f;
      }
      nc += (int)__popcll(mk); pc += (int)__popcll(mp);
    }

    // resolve pending (first use of nb => vmcnt wait lands here)
    for (int q = 0; q < pc; ++q) {
      const int p = pendC[q];          // broadcast LDS read
      const float v = pendV[q];
      const bool isadj = __any(lane < DEG && nb == p);
      if ((v - 1.0f) + (isadj ? 1.0f : 0.0f) > 0.0f) {
        if (lane == 0) lst[cur ^ 1][nc] = p;
        ++nc;                          // uniform across lanes
      }
    }

    // (b) fresh adj members: add iff not chosen and never-listed (dedup candM;
    // atomicOr return doubles as first-occurrence test). nb != nn: nn is chosen.
    bool added = false;
    if (lane < DEG && nb != nn) {
      const uint32_t w = (uint32_t)nb >> 5, bit = 1u << (nb & 31);
      if (!(chosenM[w] & bit) && !(candM[w] & bit)) {
        const uint32_t old = atomicOr(&candM[w], bit);
        added = !(old & bit);
      }
    }
    const uint64_t ma = __ballot(added);
    if (added) lst[cur ^ 1][nc + (int)__popcll(ma & lower)] = nb;
    nc += (int)__popcll(ma);

    cnt = nc;
    cur ^= 1;
  }
  if (lane == 0) out[r * (T + 1)] = self;
}

}  // namespace

extern "C" void kernel_launch(void* const* d_in, const int* in_sizes, int n_in,
                              void* d_out, int out_size, void* d_ws, size_t ws_size,
                              hipStream_t stream) {
  const float* features  = (const float*)d_in[0];
  const float* W         = (const float*)d_in[1];
  const float* b         = (const float*)d_in[2];
  const int*   neighbors = (const int*)d_in[3];
  const int*   tindex    = (const int*)d_in[4];
  int* out = (int*)d_out;

  hipLaunchKernelGGL(walk_kernel, dim3(BB), dim3(64), 0, stream,
                     features, W, b, neighbors, tindex, out);
}

// Round 7
// 24.926 us; speedup vs baseline: 1.2375x; 1.0252x over previous
//
#include <hip/hip_runtime.h>
#include <cstdint>

namespace {

constexpr int N    = 20000;   // nodes
constexpr int D    = 128;     // feature dim
constexpr int DEG  = 32;      // neighbors per node
constexpr int BB   = 1024;    // batch
constexpr int T    = 8;       // walk_times
constexpr int NW   = (N + 31) / 32;  // 625 mask words
constexpr int MAXC = 384;     // list bound (true max 32 + 8*32 = 288)

__device__ __forceinline__ uint32_t rotl32(uint32_t x, int n) {
  return (x << n) | (x >> (32 - n));
}

// Threefry-2x32, 20 rounds (Random123 / JAX threefry2x32_p).
__device__ __forceinline__ void threefry2x32(uint32_t k0, uint32_t k1,
                                             uint32_t x0, uint32_t x1,
                                             uint32_t& o0, uint32_t& o1) {
  const uint32_t ks2 = k0 ^ k1 ^ 0x1BD11BDAu;
  x0 += k0; x1 += k1;
#define TF_ROUND(r) { x0 += x1; x1 = rotl32(x1, (r)); x1 ^= x0; }
  TF_ROUND(13) TF_ROUND(15) TF_ROUND(26) TF_ROUND(6)
  x0 += k1;  x1 += ks2 + 1u;
  TF_ROUND(17) TF_ROUND(29) TF_ROUND(16) TF_ROUND(24)
  x0 += ks2; x1 += k0 + 2u;
  TF_ROUND(13) TF_ROUND(15) TF_ROUND(26) TF_ROUND(6)
  x0 += k0;  x1 += k1 + 3u;
  TF_ROUND(17) TF_ROUND(29) TF_ROUND(16) TF_ROUND(24)
  x0 += k1;  x1 += ks2 + 4u;
  TF_ROUND(13) TF_ROUND(15) TF_ROUND(26) TF_ROUND(6)
  x0 += ks2; x1 += k0 + 5u;
#undef TF_ROUND
  o0 = x0; o1 = x1;
}

// One candidate's 32 random bits for (key, flat index j): o0 ^ o1.
__device__ __forceinline__ uint32_t rbits(uint32_t k0, uint32_t k1, uint32_t j) {
  uint32_t o0, o1;
  threefry2x32(k0, k1, 0u, j, o0, o1);
  return o0 ^ o1;
}

// Exact jax.random.gumbel f32 pipeline (step 0 only): mant = top 23 bits;
// u = mant*2^-23 (or f32 tiny); g = -fl32(log(fl32(-log(u)))).
__device__ __forceinline__ float gumbel_f32(uint32_t bits) {
  const uint32_t mant = bits >> 9;
  const float u = (mant == 0u) ? 1.17549435e-38f
                               : (__uint_as_float(0x3F800000u | mant) - 1.0f);
  const float inner = -(float)log((double)u);
  return -(float)log((double)inner);
}

// Monotone (order-preserving) f32 -> u32 map for finite floats.
__device__ __forceinline__ uint32_t f2ord(float f) {
  const uint32_t b = __float_as_uint(f);
  return (b & 0x80000000u) ? ~b : (b | 0x80000000u);
}

template <int CTRL>
__device__ __forceinline__ uint32_t dppmov(uint32_t v) {
  // old = v: lanes with no valid source keep their own value (identity for max)
  return (uint32_t)__builtin_amdgcn_update_dpp((int)v, (int)v, CTRL, 0xF, 0xF, false);
}

// Exact wave64 max of packed (hi:lo) u64; result broadcast to all lanes.
__device__ __forceinline__ void wave_max64(uint32_t& hi, uint32_t& lo) {
#define RL(CTRL) { const uint32_t oh = dppmov<CTRL>(hi), ol = dppmov<CTRL>(lo); \
    if (oh > hi || (oh == hi && ol > lo)) { hi = oh; lo = ol; } }
  RL(0x111) RL(0x112) RL(0x114) RL(0x118) RL(0x142) RL(0x143)
#undef RL
  hi = (uint32_t)__builtin_amdgcn_readlane((int)hi, 63);
  lo = (uint32_t)__builtin_amdgcn_readlane((int)lo, 63);
}

__global__ __launch_bounds__(64)
void walk_kernel(const float* __restrict__ features,
                 const float* __restrict__ W,
                 const float* __restrict__ bptr,
                 const int*   __restrict__ neighbors,
                 const int*   __restrict__ train_index,
                 int* __restrict__ out)
{
  __shared__ uint32_t candM[NW];    // "ever was a candidate" (never cleared:
                                    //  any unlisted candM node is chosen)
  __shared__ uint32_t chosenM[NW];  // chosen/visited (monotone)
  __shared__ int      lst[MAXC];    // single in-place candidate list
  __shared__ float    val0[DEG];    // step-0 scores (val==1 for later steps)

  const int lane = threadIdx.x;
  const int r    = blockIdx.x;
  const int self = train_index[r];
  const uint32_t rN = (uint32_t)(r * N);
  const uint64_t lower = (1ULL << lane) - 1ULL;

  // issue self-neighbor row load ASAP
  int nbj = -1;
  if (lane < DEG) nbj = neighbors[(size_t)self * DEG + lane];

  for (int i = lane; i < NW; i += 64) { candM[i] = 0u; chosenM[i] = 0u; }

  // step keys: jax.random.split(key(42), 8) partitionable; lane k holds key k.
  uint32_t sk0, sk1;
  threefry2x32(0u, 42u, 0u, (uint32_t)lane, sk0, sk1);

  // ---- step-0 scores (fold order bit-identical to passing versions) ----
  const float bval = bptr[0];
  const float* frow = features + (size_t)self * D;
  float acc = frow[lane] * W[lane] + frow[lane + 64] * W[lane + 64];
  for (int m = 1; m < 64; m <<= 1) acc += __shfl_xor(acc, m);
  const float sx = acc;

  float sval = 0.0f;
  if (lane < DEG) {
    const float* g  = features + (size_t)nbj * D;
    const float* wy = W + D;
    float a = 0.0f;
    for (int d = 0; d < D; d += 4) {
      const float4 f = *reinterpret_cast<const float4*>(g + d);
      const float4 w = *reinterpret_cast<const float4*>(wy + d);
      a += f.x * w.x; a += f.y * w.y; a += f.z * w.z; a += f.w * w.w;
    }
    sval = fmaxf((sx + a) + bval, 0.0f);
  }

  // build step-0 list {c != self : s_c > 0}; dedup via candM atomicOr.
  bool add0 = false;
  if (lane < DEG && nbj != self && sval > 0.0f) {
    const uint32_t w = (uint32_t)nbj >> 5, bit = 1u << (nbj & 31);
    const uint32_t old = atomicOr(&candM[w], bit);
    add0 = !(old & bit);
  }
  const uint64_t m0 = __ballot(add0);
  if (add0) {
    const int p = (int)__popcll(m0 & lower);
    lst[p] = nbj; val0[p] = sval;
  }
  int cnt = (int)__popcll(m0);
  if (lane == 0) {
    chosenM[(uint32_t)self >> 5] |= 1u << (self & 31);   // chosen = self_oh
    if (cnt == 0) {  // pre-scan fallback mutates the carry: candi = self_oh
      lst[0] = self; val0[0] = 1.0f;
      candM[(uint32_t)self >> 5] |= 1u << (self & 31);
    }
  }
  if (cnt == 0) cnt = 1;

  // "zombies": chosen nodes retained in the list via adjacency (rare).
  // Static slots + mask only (rule #20: no runtime-indexed register arrays).
  int zom0 = 0, zom1 = 0, zom2 = 0, zom3 = 0, zmask = 0;

  for (int k = 0; k < T; ++k) {
    const uint32_t kk0 = (uint32_t)__builtin_amdgcn_readlane((int)sk0, k);
    const uint32_t kk1 = (uint32_t)__builtin_amdgcn_readlane((int)sk1, k);

    // ---- argmax via packed u64 max: hi = sort key, lo = 0x7FFFFFFF - c ----
    uint32_t hi = 0u, lo = 0u;
    if (k == 0) {  // scored: v = log(s) + gumbel, exact f32 pipeline (cnt<=32)
      if (lane < cnt) {
        const int c = lst[lane];
        const float v = (float)log((double)val0[lane])
                      + gumbel_f32(rbits(kk0, kk1, rN + (uint32_t)c));
        hi = f2ord(v); lo = 0x7FFFFFFFu - (uint32_t)c;
      }
    } else {
      // steps>=1: logp==0; gumbel strictly monotone in top-23-bit mantissa
      // -> argmax(g) == argmax(mant); ties -> smallest node id. 2-way ILP.
      for (int i = lane; i < cnt; i += 128) {
        const int c = lst[i];
        const uint32_t h = rbits(kk0, kk1, rN + (uint32_t)c) >> 9;
        const uint32_t l = 0x7FFFFFFFu - (uint32_t)c;
        uint32_t h2 = 0u, l2 = 0u;
        const int i2 = i + 64;
        if (i2 < cnt) {
          const int c2 = lst[i2];
          h2 = rbits(kk0, kk1, rN + (uint32_t)c2) >> 9;
          l2 = 0x7FFFFFFFu - (uint32_t)c2;
        }
        if (h  > hi || (h  == hi && l  > lo)) { hi = h;  lo = l;  }
        if (h2 > hi || (h2 == hi && l2 > lo)) { hi = h2; lo = l2; }
      }
    }
    wave_max64(hi, lo);
    const bool haveList = (cnt > 0);
    const int nn = haveList ? (int)(0x7FFFFFFFu - lo) : self;  // empty -> self

    // dependent neighbor-row load; overlaps pos-scan below
    int nb = -1;
    if (lane < DEG) nb = neighbors[(size_t)nn * DEG + lane];

    if (lane == 0) {
      out[r * (T + 1) + k + 1] = nn;
      chosenM[(uint32_t)nn >> 5] |= 1u << (nn & 31);  // same-wave DS in-order
    }

    // find nn's list position (+ its step-0 score); overlaps nb load latency
    int pos = -1; float v0f = 1.0f;
    if (haveList) {
      for (int i = lane; i < cnt; i += 64) {
        if (lst[i] == nn) { pos = i; if (k == 0) v0f = val0[i]; }
      }
      const uint64_t f = __ballot(pos >= 0);
      const int src = (int)(__ffsll((unsigned long long)f) - 1);
      pos = __shfl(pos, src);
      if (k == 0) v0f = __shfl(v0f, src);
    }

    // nn's retention: exact reference f32 semantics (candi - chosen + adj > 0)
    const bool adNN = __any(nb == nn);   // first use of nb => vmcnt wait here
    const bool stay = haveList &&
        ((k == 0) ? (((v0f - 1.0f) + (adNN ? 1.0f : 0.0f)) > 0.0f) : adNN);
    const bool wasZ = ((zmask & 1) && zom0 == nn) || ((zmask & 2) && zom1 == nn) ||
                      ((zmask & 4) && zom2 == nn) || ((zmask & 8) && zom3 == nn);

    if (haveList && !stay) {  // O(1) removal: swap last into pos
      if (pos != cnt - 1) { if (lane == 0) lst[pos] = lst[cnt - 1]; }
      --cnt;
      if (wasZ) {  // nn was a zombie and now leaves for good
        if ((zmask & 1) && zom0 == nn) zmask &= ~1;
        else if ((zmask & 2) && zom1 == nn) zmask &= ~2;
        else if ((zmask & 4) && zom2 == nn) zmask &= ~4;
        else if ((zmask & 8) && zom3 == nn) zmask &= ~8;
      }
    } else if (haveList && stay && !wasZ) {  // chosen node retained -> zombie
      if      (!(zmask & 1)) { zom0 = nn; zmask |= 1; }
      else if (!(zmask & 2)) { zom1 = nn; zmask |= 2; }
      else if (!(zmask & 4)) { zom2 = nn; zmask |= 4; }
      else                   { zom3 = nn; zmask |= 8; }
    }

    // zombie re-test (rare, wave-uniform skip): z stays iff z in nb(nn)
    if (zmask) {
#define ZTEST(BIT, Z) \
      if ((zmask & BIT) && Z != nn) { \
        const bool adz = __any(nb == Z); \
        if (!adz) { \
          int pz = -1; \
          for (int i = lane; i < cnt; i += 64) if (lst[i] == Z) pz = i; \
          const uint64_t fz = __ballot(pz >= 0); \
          const int sz = (int)(__ffsll((unsigned long long)fz) - 1); \
          pz = __shfl(pz, sz); \
          if (pz != cnt - 1) { if (lane == 0) lst[pz] = lst[cnt - 1]; } \
          --cnt; \
          zmask &= ~BIT; \
        } \
      }
      ZTEST(1, zom0) ZTEST(2, zom1) ZTEST(4, zom2) ZTEST(8, zom3)
#undef ZTEST
    }

    // (b) fresh adj members: add iff not chosen and never-listed (dedup candM;
    // atomicOr return doubles as first-occurrence test). nn excluded explicitly.
    bool added = false;
    if (lane < DEG && nb != nn) {
      const uint32_t w = (uint32_t)nb >> 5, bit = 1u << (nb & 31);
      if (!(chosenM[w] & bit) && !(candM[w] & bit)) {
        const uint32_t old = atomicOr(&candM[w], bit);
        added = !(old & bit);
      }
    }
    const uint64_t ma = __ballot(added);
    if (added) lst[cnt + (int)__popcll(ma & lower)] = nb;
    cnt += (int)__popcll(ma);
  }
  if (lane == 0) out[r * (T + 1)] = self;
}

}  // namespace

extern "C" void kernel_launch(void* const* d_in, const int* in_sizes, int n_in,
                              void* d_out, int out_size, void* d_ws, size_t ws_size,
                              hipStream_t stream) {
  const float* features  = (const float*)d_in[0];
  const float* W         = (const float*)d_in[1];
  const float* b         = (const float*)d_in[2];
  const int*   neighbors = (const int*)d_in[3];
  const int*   tindex    = (const int*)d_in[4];
  int* out = (int*)d_out;

  hipLaunchKernelGGL(walk_kernel, dim3(BB), dim3(64), 0, stream,
                     features, W, b, neighbors, tindex, out);
}

// Round 9
// 23.469 us; speedup vs baseline: 1.3143x; 1.0621x over previous
//
#include <hip/hip_runtime.h>
#include <cstdint>

namespace {

constexpr int N    = 20000;   // nodes
constexpr int D    = 128;     // feature dim
constexpr int DEG  = 32;      // neighbors per node
constexpr int BB   = 1024;    // batch
constexpr int T    = 8;       // walk_times
constexpr int NC   = (N + 15) / 16;  // 1250 combined-mask words (2 bits/node)
constexpr int MAXC = 384;     // list bound (true max ~292)

__device__ __forceinline__ uint32_t rotl32(uint32_t x, int n) {
  return (x << n) | (x >> (32 - n));
}

// Threefry-2x32, 20 rounds (Random123 / JAX threefry2x32_p).
__device__ __forceinline__ void threefry2x32(uint32_t k0, uint32_t k1,
                                             uint32_t x0, uint32_t x1,
                                             uint32_t& o0, uint32_t& o1) {
  const uint32_t ks2 = k0 ^ k1 ^ 0x1BD11BDAu;
  x0 += k0; x1 += k1;
#define TF_ROUND(r) { x0 += x1; x1 = rotl32(x1, (r)); x1 ^= x0; }
  TF_ROUND(13) TF_ROUND(15) TF_ROUND(26) TF_ROUND(6)
  x0 += k1;  x1 += ks2 + 1u;
  TF_ROUND(17) TF_ROUND(29) TF_ROUND(16) TF_ROUND(24)
  x0 += ks2; x1 += k0 + 2u;
  TF_ROUND(13) TF_ROUND(15) TF_ROUND(26) TF_ROUND(6)
  x0 += k0;  x1 += k1 + 3u;
  TF_ROUND(17) TF_ROUND(29) TF_ROUND(16) TF_ROUND(24)
  x0 += k1;  x1 += ks2 + 4u;
  TF_ROUND(13) TF_ROUND(15) TF_ROUND(26) TF_ROUND(6)
  x0 += ks2; x1 += k0 + 5u;
#undef TF_ROUND
  o0 = x0; o1 = x1;
}

__device__ __forceinline__ uint32_t rbits(uint32_t k0, uint32_t k1, uint32_t j) {
  uint32_t o0, o1;
  threefry2x32(k0, k1, 0u, j, o0, o1);
  return o0 ^ o1;
}

// Exact jax.random.gumbel f32 pipeline (step 0 only).
__device__ __forceinline__ float gumbel_f32(uint32_t bits) {
  const uint32_t mant = bits >> 9;
  const float u = (mant == 0u) ? 1.17549435e-38f
                               : (__uint_as_float(0x3F800000u | mant) - 1.0f);
  const float inner = -(float)log((double)u);
  return -(float)log((double)inner);
}

// Monotone f32 -> u32 map (finite floats).
__device__ __forceinline__ uint32_t f2ord(float f) {
  const uint32_t b = __float_as_uint(f);
  return (b & 0x80000000u) ? ~b : (b | 0x80000000u);
}

template <int CTRL>
__device__ __forceinline__ uint32_t dppmov(uint32_t v) {
  return (uint32_t)__builtin_amdgcn_update_dpp((int)v, (int)v, CTRL, 0xF, 0xF, false);
}

// Exact wave64 max of packed (hi:lo) u64; result broadcast to all lanes.
__device__ __forceinline__ void wave_max64(uint32_t& hi, uint32_t& lo) {
#define RL(CTRL) { const uint32_t oh = dppmov<CTRL>(hi), ol = dppmov<CTRL>(lo); \
    if (oh > hi || (oh == hi && ol > lo)) { hi = oh; lo = ol; } }
  RL(0x111) RL(0x112) RL(0x114) RL(0x118) RL(0x142) RL(0x143)
#undef RL
  hi = (uint32_t)__builtin_amdgcn_readlane((int)hi, 63);
  lo = (uint32_t)__builtin_amdgcn_readlane((int)lo, 63);
}

// combined mask helpers: word holds 16 nodes x {cand bit, chosen bit}
__device__ __forceinline__ uint32_t cwd(int n)  { return (uint32_t)n >> 4; }
__device__ __forceinline__ uint32_t cbit(int n) { return 1u << (((uint32_t)n & 15u) << 1); }
// chosen bit = cbit << 1

__global__ __launch_bounds__(64)
void walk_kernel(const float* __restrict__ features,
                 const float* __restrict__ W,
                 const float* __restrict__ bptr,
                 const int*   __restrict__ neighbors,
                 const int*   __restrict__ train_index,
                 int* __restrict__ out)
{
  __shared__ uint32_t comb[NC];   // bit0(cand)/bit1(chosen) per node
  __shared__ int      lst[MAXC];  // in-place candidate list
  __shared__ float    val0[DEG];  // step-0 scores (val==1 afterwards)

  const int lane = threadIdx.x;
  const int r    = blockIdx.x;
  const int self = train_index[r];
  const uint32_t rN = (uint32_t)(r * N);
  const uint64_t lower = (1ULL << lane) - 1ULL;

  int nbj = -1;
  if (lane < DEG) nbj = neighbors[(size_t)self * DEG + lane];

  {  // clear combined mask (64-bit stores, 10 iterations)
    uint64_t* c8 = reinterpret_cast<uint64_t*>(comb);
    for (int i = lane; i < NC / 2; i += 64) c8[i] = 0ull;
  }

  // step keys: jax.random.split(key(42), 8) partitionable; lane k holds key k.
  // sk0/sk1 are NEVER written after this point (R8's bug was a hidden
  // assignment to sk0 inside the k==0 expression, clobbering step>=1 keys).
  uint32_t sk0, sk1;
  threefry2x32(0u, 42u, 0u, (uint32_t)lane, sk0, sk1);

  // ---- step-0 scores (fold order bit-identical to passing versions) ----
  const float bval = bptr[0];
  const float* frow = features + (size_t)self * D;
  float acc = frow[lane] * W[lane] + frow[lane + 64] * W[lane + 64];
  for (int m = 1; m < 64; m <<= 1) acc += __shfl_xor(acc, m);
  const float sx = acc;

  float sval = 0.0f;
  if (lane < DEG) {
    const float* g  = features + (size_t)nbj * D;
    const float* wy = W + D;
    float a = 0.0f;
    for (int d = 0; d < D; d += 4) {
      const float4 f = *reinterpret_cast<const float4*>(g + d);
      const float4 w = *reinterpret_cast<const float4*>(wy + d);
      a += f.x * w.x; a += f.y * w.y; a += f.z * w.z; a += f.w * w.w;
    }
    sval = fmaxf((sx + a) + bval, 0.0f);
  }

  // build step-0 list {c != self : s_c > 0}; dedup via single atomicOr
  bool add0 = false;
  if (lane < DEG && nbj != self && sval > 0.0f) {
    const uint32_t old = atomicOr(&comb[cwd(nbj)], cbit(nbj));
    add0 = !(old & cbit(nbj));
  }
  const uint64_t m0 = __ballot(add0);
  if (add0) {
    const int p = (int)__popcll(m0 & lower);
    lst[p] = nbj; val0[p] = sval;
  }
  int cnt = (int)__popcll(m0);
  if (lane == 0) {
    atomicOr(&comb[cwd(self)], cbit(self) << 1);   // chosen = self_oh
    if (cnt == 0) {  // pre-scan fallback mutates the carry: candi = self_oh
      lst[0] = self; val0[0] = 1.0f;
      atomicOr(&comb[cwd(self)], cbit(self));
    }
  }
  if (cnt == 0) cnt = 1;

  // zombies: chosen nodes retained via adjacency (rare). Static slots (rule #20).
  int zom0 = 0, zom1 = 0, zom2 = 0, zom3 = 0, zmask = 0;
  uint32_t hiP = 0u, loP = 0u;  // pipelined next-step argmax partials

  for (int k = 0; k < T; ++k) {
    // ---- argmax: hi = sort key, lo = (0x7FFFFF - c)<<9 | pos ----
    // (equal key -> max lo -> min c; pos is payload — unique per c, dedup'd list)
    uint32_t hi, lo;
    if (k == 0) {  // scored: v = log(s) + gumbel, exact f32 pipeline (cnt<=32)
      const uint32_t kk0 = (uint32_t)__builtin_amdgcn_readlane((int)sk0, 0);
      const uint32_t kk1 = (uint32_t)__builtin_amdgcn_readlane((int)sk1, 0);
      hi = 0u; lo = 0u;
      if (lane < cnt) {
        const int c = lst[lane];
        const float v = (float)log((double)val0[lane])
                      + gumbel_f32(rbits(kk0, kk1, rN + (uint32_t)c));
        hi = f2ord(v); lo = ((0x7FFFFFu - (uint32_t)c) << 9) | (uint32_t)lane;
      }
    } else {
      hi = hiP; lo = loP;  // precomputed during step k-1's nb shadow
    }
    wave_max64(hi, lo);
    const bool haveList = (cnt > 0);
    const int nn  = haveList ? (int)(0x7FFFFFu - (lo >> 9)) : self;
    const int pos = (int)(lo & 0x1FFu);

    if (lane == 0) out[r * (T + 1) + k + 1] = nn;
    if (k == T - 1) break;   // list is dead after the last draw

    // dependent neighbor-row load; overlaps everything until first use of nb
    int nb = -1;
    if (lane < DEG) nb = neighbors[(size_t)nn * DEG + lane];

    if (lane == 0) atomicOr(&comb[cwd(nn)], cbit(nn) << 1);  // chosen |= nn

    float v0f = 1.0f;
    if (k == 0 && haveList) v0f = val0[pos];  // broadcast read (pre-removal)

    // speculative O(1) removal of nn (re-appended below iff stay; order moot)
    if (haveList) {
      const int last = lst[cnt - 1];            // broadcast read
      if (pos != cnt - 1 && lane == 0) lst[pos] = last;
      --cnt;
    }

    // next-step keys (SGPR via readlane)
    const uint32_t nk0 = (uint32_t)__builtin_amdgcn_readlane((int)sk0, k + 1);
    const uint32_t nk1 = (uint32_t)__builtin_amdgcn_readlane((int)sk1, k + 1);

    // pipelined partial scan for step k+1 over survivors — runs in nb's shadow
    hiP = 0u; loP = 0u;
    for (int i = lane; i < cnt; i += 64) {
      const int c = lst[i];
      const uint32_t h = rbits(nk0, nk1, rN + (uint32_t)c) >> 9;
      const uint32_t l = ((0x7FFFFFu - (uint32_t)c) << 9) | (uint32_t)i;
      if (h > hiP || (h == hiP && l > loP)) { hiP = h; loP = l; }
    }

    // ---- nb-dependent resolution (vmcnt wait lands here) ----
    const bool adNN = __any(nb == nn);
    const bool wasZ = ((zmask & 1) && zom0 == nn) || ((zmask & 2) && zom1 == nn) ||
                      ((zmask & 4) && zom2 == nn) || ((zmask & 8) && zom3 == nn);
    const bool stay = haveList &&
        ((k == 0) ? (((v0f - 1.0f) + (adNN ? 1.0f : 0.0f)) > 0.0f) : adNN);

    if (stay) {  // rare: re-append nn; track as zombie; merge its key
      if (lane == 0) lst[cnt] = nn;
      const int posN = cnt; ++cnt;
      if (!wasZ) {
        if      (!(zmask & 1)) { zom0 = nn; zmask |= 1; }
        else if (!(zmask & 2)) { zom1 = nn; zmask |= 2; }
        else if (!(zmask & 4)) { zom2 = nn; zmask |= 4; }
        else                   { zom3 = nn; zmask |= 8; }
      }
      const uint32_t h = rbits(nk0, nk1, rN + (uint32_t)nn) >> 9;
      const uint32_t l = ((0x7FFFFFu - (uint32_t)nn) << 9) | (uint32_t)posN;
      if (h > hiP || (h == hiP && l > loP)) { hiP = h; loP = l; }
    } else if (wasZ) {  // nn was a zombie and now leaves for good
      if ((zmask & 1) && zom0 == nn) zmask &= ~1;
      else if ((zmask & 2) && zom1 == nn) zmask &= ~2;
      else if ((zmask & 4) && zom2 == nn) zmask &= ~4;
      else if ((zmask & 8) && zom3 == nn) zmask &= ~8;
    }

    // zombie retests (rare, wave-uniform skip): z stays iff z in nb(nn)
    bool zdrop = false;
    if (zmask) {
#define ZTEST(BIT, Z) \
      if ((zmask & BIT) && Z != nn) { \
        if (!__any(nb == Z)) { \
          int pz = -1; \
          for (int i = lane; i < cnt; i += 64) if (lst[i] == Z) pz = i; \
          const uint64_t fz = __ballot(pz >= 0); \
          const int sz = (int)(__ffsll((unsigned long long)fz) - 1); \
          pz = __shfl(pz, sz); \
          const int lastz = lst[cnt - 1]; \
          if (pz != cnt - 1 && lane == 0) lst[pz] = lastz; \
          --cnt; zmask &= ~BIT; zdrop = true; \
        } \
      }
      ZTEST(1, zom0) ZTEST(2, zom1) ZTEST(4, zom2) ZTEST(8, zom3)
#undef ZTEST
    }
    if (zdrop) {  // rare: partials may reference dropped/moved entries — redo
      hiP = 0u; loP = 0u;
      for (int i = lane; i < cnt; i += 64) {
        const int c = lst[i];
        const uint32_t h = rbits(nk0, nk1, rN + (uint32_t)c) >> 9;
        const uint32_t l = ((0x7FFFFFu - (uint32_t)c) << 9) | (uint32_t)i;
        if (h > hiP || (h == hiP && l > loP)) { hiP = h; loP = l; }
      }
    }

    // (b) fresh adj members — ONE atomic: old word tests cand AND chosen bits.
    // (nn's chosen bit was set above; same-wave DS ops complete in order.)
    bool added = false;
    const int nbv = nb;
    if (lane < DEG) {
      const uint32_t old = atomicOr(&comb[cwd(nbv)], cbit(nbv));
      added = !(old & (cbit(nbv) | (cbit(nbv) << 1)));
    }
    const uint64_t ma = __ballot(added);
    const int mypos = cnt + (int)__popcll(ma & lower);
    if (added) {
      lst[mypos] = nbv;
      const uint32_t h = rbits(nk0, nk1, rN + (uint32_t)nbv) >> 9;
      const uint32_t l = ((0x7FFFFFu - (uint32_t)nbv) << 9) | (uint32_t)mypos;
      if (h > hiP || (h == hiP && l > loP)) { hiP = h; loP = l; }
    }
    cnt += (int)__popcll(ma);
  }
  if (lane == 0) out[r * (T + 1)] = self;
}

}  // namespace

extern "C" void kernel_launch(void* const* d_in, const int* in_sizes, int n_in,
                              void* d_out, int out_size, void* d_ws, size_t ws_size,
                              hipStream_t stream) {
  const float* features  = (const float*)d_in[0];
  const float* W         = (const float*)d_in[1];
  const float* b         = (const float*)d_in[2];
  const int*   neighbors = (const int*)d_in[3];
  const int*   tindex    = (const int*)d_in[4];
  int* out = (int*)d_out;

  hipLaunchKernelGGL(walk_kernel, dim3(BB), dim3(64), 0, stream,
                     features, W, b, neighbors, tindex, out);
}